// Round 3
// baseline (94.087 us; speedup 1.0000x reference)
//
#include <hip/hip_runtime.h>

#define NN 8192
#define DD 128
#define BM 128
#define NT 16            // j-tiles per block (fast path)
#define NTILE (NN / BM)  // 64

typedef __attribute__((ext_vector_type(8))) short bf16x8;
typedef __attribute__((ext_vector_type(4))) float f32x4;

__device__ __forceinline__ ushort f2bf(float x) {
    unsigned u = __float_as_uint(x);
    unsigned r = u + 0x7FFFu + ((u >> 16) & 1u);
    return (ushort)(r >> 16);
}

__device__ __forceinline__ void async16(void* lds, const void* g) {
    __builtin_amdgcn_global_load_lds(
        (const __attribute__((address_space(1))) unsigned*)g,
        (__attribute__((address_space(3))) unsigned*)lds, 16, 0, 0);
}

// Kernel 0: sq[i] = ||f_i||^2; Fbf = bf16(F) (fast path); zero the done-counter.
__global__ void prep_kernel(const float* __restrict__ F, ushort* __restrict__ Fbf,
                            float* __restrict__ sq, int* counter, int doFbf) {
    if (blockIdx.x == 0 && threadIdx.x == 0 && counter) *counter = 0;
    int gtid = blockIdx.x * blockDim.x + threadIdx.x;
    int row  = gtid >> 6;
    int lane = threadIdx.x & 63;
    const float2 v = *(const float2*)(F + (size_t)row * DD + lane * 2);
    if (doFbf)
        ((ushort2*)(Fbf + (size_t)row * DD))[lane] = make_ushort2(f2bf(v.x), f2bf(v.y));
    float s = v.x * v.x + v.y * v.y;
    #pragma unroll
    for (int off = 32; off > 0; off >>= 1) s += __shfl_down(s, off);
    if (lane == 0) sq[row] = s;
}

// ---------------- fast path: persistent j-loop tile kernel ----------------
// One body iteration: stage F_j[t+1] (async->WBUF), prefetch S[t+1] (->SVN),
// MFMA on RBUF, consume SVC, counted-vmcnt + raw barrier (S[t+1] stays in flight).
#define BODY(T, SVC, SJC, SVN, SJN, RBUF, WBUF)                               \
  {                                                                           \
    const int t_ = (T);                                                       \
    if (t_ < NT - 1) {                                                        \
      const int jr0 = jg0 + (t_ + 1) * BM;                                    \
      _Pragma("unroll")                                                       \
      for (int it = 0; it < 4; ++it) {                                        \
        const int c = it * 8 + w;                                             \
        const int row = c * 4 + (l >> 4);                                     \
        const int src = ((l & 15) * 16) ^ ((row & 7) << 4);                   \
        async16((char*)(WBUF) + c * 1024,                                     \
                (const char*)(Fbf + (size_t)(jr0 + row) * DD) + src);         \
      }                                                                       \
      __builtin_amdgcn_sched_barrier(0);                                      \
      const float* sb_ = sbase + jr0;                                         \
      _Pragma("unroll")                                                       \
      for (int ct = 0; ct < 8; ++ct)                                          \
        SVN[ct] = *(const float4*)(sb_ + (size_t)ct * 16 * NN);               \
      SJN = *(const float4*)(sq + jr0 + jcol);                                \
      __builtin_amdgcn_sched_barrier(0);                                      \
    }                                                                         \
    bf16x8 af[4];                                                             \
    {                                                                         \
      const int row = jw + fr;                                                \
      const int sw = (row & 7) << 4;                                          \
      _Pragma("unroll")                                                       \
      for (int kk = 0; kk < 4; ++kk)                                          \
        af[kk] = *(const bf16x8*)((const char*)RBUF + row * 256 +             \
                                  ((kk * 64 + g * 16) ^ sw));                 \
    }                                                                         \
    f32x4 acc[8];                                                             \
    _Pragma("unroll")                                                         \
    for (int ct = 0; ct < 8; ++ct) acc[ct] = (f32x4){0.f, 0.f, 0.f, 0.f};     \
    _Pragma("unroll")                                                         \
    for (int ct = 0; ct < 8; ++ct) {                                          \
      const int row = ct * 16 + fr;                                           \
      const int sw = (row & 7) << 4;                                          \
      _Pragma("unroll")                                                       \
      for (int kk = 0; kk < 4; ++kk) {                                        \
        const bf16x8 bf_ = *(const bf16x8*)((const char*)lI + row * 256 +     \
                                            ((kk * 64 + g * 16) ^ sw));       \
        acc[ct] = __builtin_amdgcn_mfma_f32_16x16x32_bf16(af[kk], bf_,        \
                                                          acc[ct], 0, 0, 0);  \
      }                                                                       \
    }                                                                         \
    _Pragma("unroll")                                                         \
    for (int ct = 0; ct < 8; ++ct) {                                          \
      const float4 s4 = SVC[ct];                                              \
      const float c0 = si[ct] + SJC.x, c1 = si[ct] + SJC.y,                   \
                  c2 = si[ct] + SJC.z, c3 = si[ct] + SJC.w;                   \
      part0 += s4.x * (c0 - 2.f * acc[ct][0]);                                \
      part1 += s4.y * (c1 - 2.f * acc[ct][1]);                                \
      part0 += s4.z * (c2 - 2.f * acc[ct][2]);                                \
      part1 += s4.w * (c3 - 2.f * acc[ct][3]);                                \
    }                                                                         \
    if (t_ < NT - 1) {                                                        \
      asm volatile("s_waitcnt vmcnt(9)" ::: "memory");                        \
      __builtin_amdgcn_sched_barrier(0);                                      \
      __builtin_amdgcn_s_barrier();                                           \
    }                                                                         \
  }

__global__ __launch_bounds__(512, 2) void tile_loop_kernel(
        const ushort* __restrict__ Fbf, const float* __restrict__ S,
        const float* __restrict__ sq, float* __restrict__ partials,
        int* __restrict__ counter, float* __restrict__ out) {
    __shared__ ushort lI[BM * DD];    // F_i panel (fixed per block), swizzled
    __shared__ ushort lJ0[BM * DD];   // F_j double buffer
    __shared__ ushort lJ1[BM * DD];
    __shared__ float  red[8];

    const int bi  = blockIdx.y;          // 0..63
    const int jg  = blockIdx.x;          // 0..3
    const int gi  = bi * BM;
    const int jg0 = jg * (NT * BM);      // 2048-wide j column group
    const int tid = threadIdx.x;
    const int w = tid >> 6, l = tid & 63;
    const int fr = l & 15, g = l >> 4;
    const int jw = w * 16;               // wave's 16-col j window in tile
    const int jcol = jw + g * 4;

    // ---- prologue: stage lI + lJ0 (8 async/thread), then si/S[0] (17 loads) ----
    #pragma unroll
    for (int it = 0; it < 4; ++it) {
        const int c = it * 8 + w;
        const int row = c * 4 + (l >> 4);
        const int src = ((l & 15) * 16) ^ ((row & 7) << 4);
        async16((char*)lI  + c * 1024, (const char*)(Fbf + (size_t)(gi  + row) * DD) + src);
        async16((char*)lJ0 + c * 1024, (const char*)(Fbf + (size_t)(jg0 + row) * DD) + src);
    }
    __builtin_amdgcn_sched_barrier(0);

    float si[8];
    #pragma unroll
    for (int ct = 0; ct < 8; ++ct) si[ct] = sq[gi + ct * 16 + fr];

    const float* sbase = S + (size_t)(gi + fr) * NN + jcol;
    float4 svA[8], svB[8], sjA, sjB;
    #pragma unroll
    for (int ct = 0; ct < 8; ++ct)
        svA[ct] = *(const float4*)(sbase + jg0 + (size_t)ct * 16 * NN);
    sjA = *(const float4*)(sq + jg0 + jcol);
    __builtin_amdgcn_sched_barrier(0);
    asm volatile("s_waitcnt vmcnt(17)" ::: "memory");  // staging (first 8) retired
    __builtin_amdgcn_sched_barrier(0);
    __builtin_amdgcn_s_barrier();

    float part0 = 0.f, part1 = 0.f;

    for (int tt = 0; tt < NT; tt += 2) {
        BODY(tt,     svA, sjA, svB, sjB, lJ0, lJ1);
        BODY(tt + 1, svB, sjB, svA, sjA, lJ1, lJ0);
    }

    // ---- deterministic reduction ----
    float part = part0 + part1;
    #pragma unroll
    for (int off = 32; off > 0; off >>= 1) part += __shfl_down(part, off);
    if (l == 0) red[w] = part;
    __syncthreads();
    if (tid == 0) {
        float r = ((red[0] + red[1]) + (red[2] + red[3])) +
                  ((red[4] + red[5]) + (red[6] + red[7]));
        const int bx = blockIdx.y * gridDim.x + blockIdx.x;
        partials[bx] = r;
        __threadfence();
        if (atomicAdd(counter, 1) == 255) {   // last block: fixed-order final sum
            __threadfence();
            volatile const float* vp = partials;
            float tot = 0.f;
            for (int i = 0; i < 256; ++i) tot += vp[i];
            out[0] = tot;
        }
    }
}

// ---------------- fallback path (no Fbf workspace): R2-style ----------------
__global__ __launch_bounds__(256, 2) void tile_fb_kernel(
        const float* __restrict__ F, const float* __restrict__ S,
        const float* __restrict__ sq, float* __restrict__ partials) {
    __shared__ ushort lI[BM * DD];
    __shared__ ushort lJ[BM * DD];
    __shared__ float  sqi[BM];
    __shared__ float  sqj[BM];
    __shared__ float  red[4];

    const int bi = blockIdx.y, bj = blockIdx.x;
    const int gi = bi * BM, gj = bj * BM;
    const int tid = threadIdx.x;
    const int w = tid >> 6, l = tid & 63;

    const int r0 = tid >> 5;
    const int c4 = (tid & 31) * 4;
    #pragma unroll
    for (int it = 0; it < 16; ++it) {
        const int row = it * 8 + r0;
        const float4 va = *(const float4*)(F + (size_t)(gi + row) * DD + c4);
        const float4 vb = *(const float4*)(F + (size_t)(gj + row) * DD + c4);
        int byte = row * 256 + c4 * 2;
        byte ^= (row & 7) << 4;
        *(ushort4*)((char*)lI + byte) =
            make_ushort4(f2bf(va.x), f2bf(va.y), f2bf(va.z), f2bf(va.w));
        *(ushort4*)((char*)lJ + byte) =
            make_ushort4(f2bf(vb.x), f2bf(vb.y), f2bf(vb.z), f2bf(vb.w));
    }
    if (tid < 128) sqi[tid] = sq[gi + tid];
    else           sqj[tid - 128] = sq[gj + tid - 128];
    __syncthreads();

    const int fr = l & 15;
    const int g  = l >> 4;
    const int jw = w * 32;

    float4 sv0[8], sv1[8];
    #pragma unroll
    for (int ct = 0; ct < 8; ++ct) {
        const float* srow = S + (size_t)(gi + ct * 16 + fr) * NN + gj + jw + g * 4;
        sv0[ct] = *(const float4*)(srow);
        sv1[ct] = *(const float4*)(srow + 16);
    }

    bf16x8 afrag[2][4];
    #pragma unroll
    for (int kk = 0; kk < 4; ++kk) {
        int row = jw + fr;
        int byte = row * 256 + kk * 64 + g * 16; byte ^= (row & 7) << 4;
        afrag[0][kk] = *(const bf16x8*)((const char*)lJ + byte);
        row = jw + 16 + fr;
        byte = row * 256 + kk * 64 + g * 16; byte ^= (row & 7) << 4;
        afrag[1][kk] = *(const bf16x8*)((const char*)lJ + byte);
    }

    f32x4 acc[2][8];
    #pragma unroll
    for (int ct = 0; ct < 8; ++ct) {
        acc[0][ct] = (f32x4){0.f, 0.f, 0.f, 0.f};
        acc[1][ct] = (f32x4){0.f, 0.f, 0.f, 0.f};
    }
    #pragma unroll
    for (int ct = 0; ct < 8; ++ct) {
        #pragma unroll
        for (int kk = 0; kk < 4; ++kk) {
            const int row = ct * 16 + fr;
            int byte = row * 256 + kk * 64 + g * 16; byte ^= (row & 7) << 4;
            const bf16x8 bfrag = *(const bf16x8*)((const char*)lI + byte);
            acc[0][ct] = __builtin_amdgcn_mfma_f32_16x16x32_bf16(afrag[0][kk], bfrag, acc[0][ct], 0, 0, 0);
            acc[1][ct] = __builtin_amdgcn_mfma_f32_16x16x32_bf16(afrag[1][kk], bfrag, acc[1][ct], 0, 0, 0);
        }
    }

    const float4 sj0 = *(const float4*)(sqj + jw + g * 4);
    const float4 sj1 = *(const float4*)(sqj + jw + 16 + g * 4);
    float part = 0.f;
    #pragma unroll
    for (int ct = 0; ct < 8; ++ct) {
        const float sic = sqi[ct * 16 + fr];
        const float4 s0 = sv0[ct], s1 = sv1[ct];
        part += s0.x * (sic + sj0.x - 2.f * acc[0][ct][0]);
        part += s0.y * (sic + sj0.y - 2.f * acc[0][ct][1]);
        part += s0.z * (sic + sj0.z - 2.f * acc[0][ct][2]);
        part += s0.w * (sic + sj0.w - 2.f * acc[0][ct][3]);
        part += s1.x * (sic + sj1.x - 2.f * acc[1][ct][0]);
        part += s1.y * (sic + sj1.y - 2.f * acc[1][ct][1]);
        part += s1.z * (sic + sj1.z - 2.f * acc[1][ct][2]);
        part += s1.w * (sic + sj1.w - 2.f * acc[1][ct][3]);
    }

    #pragma unroll
    for (int off = 32; off > 0; off >>= 1) part += __shfl_down(part, off);
    if (l == 0) red[w] = part;
    __syncthreads();
    if (tid == 0)
        partials[blockIdx.y * gridDim.x + blockIdx.x] = (red[0] + red[1]) + (red[2] + red[3]);
}

__global__ void reduce_kernel(const float* __restrict__ partials, float* __restrict__ out) {
    __shared__ float sm[256];
    const int t = threadIdx.x;
    float s = 0.f;
    for (int i = t; i < NTILE * NTILE; i += 256) s += partials[i];
    sm[t] = s;
    __syncthreads();
    for (int off = 128; off > 0; off >>= 1) {
        if (t < off) sm[t] += sm[t + off];
        __syncthreads();
    }
    if (t == 0) out[0] = sm[0];
}

extern "C" void kernel_launch(void* const* d_in, const int* in_sizes, int n_in,
                              void* d_out, int out_size, void* d_ws, size_t ws_size,
                              hipStream_t stream) {
    const float* F = (const float*)d_in[0];
    const float* S = (const float*)d_in[1];
    float* sq        = (float*)d_ws;                        // 8192 floats
    float* partials  = sq + NN;                             // 256 floats (fast) / 4096 (fb)
    int*   counter   = (int*)((char*)d_ws + 33792);
    ushort* Fbf      = (ushort*)((char*)d_ws + 49152);      // 2 MB
    float* out       = (float*)d_out;

    const size_t need = 49152 + (size_t)NN * DD * 2 + 256;
    const int fast = (ws_size >= need) ? 1 : 0;

    prep_kernel<<<NN / 4, 256, 0, stream>>>(F, Fbf, sq, fast ? counter : nullptr, fast);
    if (fast) {
        tile_loop_kernel<<<dim3(4, 64), 512, 0, stream>>>(Fbf, S, sq, partials, counter, out);
    } else {
        tile_fb_kernel<<<dim3(NTILE, NTILE), 256, 0, stream>>>(F, S, sq, partials);
        reduce_kernel<<<1, 256, 0, stream>>>(partials, out);
    }
}